// Round 11
// baseline (136.400 us; speedup 1.0000x reference)
//
#include <hip/hip_runtime.h>
#include <math.h>

#define BB 32
#define SS 2048
#define HH 1024
#define AA 256
#define NEGV (-1e20f)
#define BK 32
#define CH 64
#define SCH (SS / CH)   // 32
#define NT (HH / BK)    // 32

typedef _Float16 half8 __attribute__((ext_vector_type(8)));
typedef float f32x4 __attribute__((ext_vector_type(4)));

__device__ inline void async_lds16(const void* g, void* l) {
    __builtin_amdgcn_global_load_lds(
        (const __attribute__((address_space(1))) unsigned int*)g,
        (__attribute__((address_space(3))) unsigned int*)l, 16, 0, 0);
}

__device__ inline half8 cvt8(float4 a, float4 b) {
    half8 h;
    h[0] = (_Float16)a.x; h[1] = (_Float16)a.y;
    h[2] = (_Float16)a.z; h[3] = (_Float16)a.w;
    h[4] = (_Float16)b.x; h[5] = (_Float16)b.y;
    h[6] = (_Float16)b.z; h[7] = (_Float16)b.w;
    return h;
}

// ============ PREP ==========================================================
// blocks [0,128):    W1 -> f16, K-major 16KB tiles (tile kt: unit = col*4+ks)
// blocks [128,2176): c[b,a] = bias[a] + h_t[b,:].W[a,H:2H]
// blocks [2176,2208): per-b compact list {s: count[s]>b} (pad 64) + pcnt
__global__ __launch_bounds__(256) void k_prep(const float* __restrict__ W,
                                              const float* __restrict__ h_t,
                                              const float* __restrict__ bias,
                                              const int* __restrict__ mask,
                                              _Float16* __restrict__ W16t,
                                              float* __restrict__ c,
                                              int* __restrict__ sList,
                                              int* __restrict__ cntb,
                                              int* __restrict__ pcnt) {
    const int blk = blockIdx.x;
    const int tid = threadIdx.x;
    __shared__ int lcnt;

    if (blk < 128) {                        // ---- role A: W16 tiled cast
        int idx = blk * 256 + tid;          // unit id, < 32768
        int kt = idx >> 10;
        int u  = idx & 1023;
        int col = u >> 2, ks = u & 3;
        const float* src = W + (size_t)col * 2 * HH + kt * BK + ks * 8;
        float4 a0 = *(const float4*)src;
        float4 a1 = *(const float4*)(src + 4);
        *reinterpret_cast<half8*>(W16t + (size_t)idx * 8) = cvt8(a0, a1);
        return;
    }
    if (blk < 2176) {                       // ---- role B: ctx GEMV
        int wave = tid >> 6;
        int lane = tid & 63;
        int pair = (blk - 128) * 4 + wave;  // < B*A = 8192
        int b = pair >> 8;
        int a = pair & (AA - 1);
        const float* ht = h_t + (size_t)b * HH;
        const float* w2 = W + (size_t)a * 2 * HH + HH;
        float acc = 0.f;
        for (int k = lane; k < HH; k += 64)
            acc += ht[k] * w2[k];
        for (int off = 32; off; off >>= 1)
            acc += __shfl_down(acc, off, 64);
        if (lane == 0) c[pair] = acc + bias[a];
        return;
    }
    // ---- role C: compaction + prefix counts
    const int b = blk - 2176;
    if (tid == 0) lcnt = 0;
    __syncthreads();
    int* lst = sList + b * SS;
#pragma unroll
    for (int i = 0; i < 8; ++i) {
        int s = tid + i * 256;
        int pref = 0, tot = 0;
#pragma unroll
        for (int bb = 0; bb < BB; ++bb) {
            int mv = (mask[bb * SS + s] != 0);
            tot += mv;
            if (bb <= b) pref += mv;
        }
        pcnt[b * SS + s] = pref;
        if (tot > b) { int p = atomicAdd(&lcnt, 1); lst[p] = s; }
    }
    __syncthreads();
    const int m = lcnt;
    if (tid == 0) cntb[b] = m;
    if (m > 0) {
        int padded = (m + 63) & ~63;
        int first = lst[0];
        for (int j = m + tid; j < padded; j += 256) lst[j] = first;
    }
}

// ============ K2: MFMA f16 score GEMM, 64x256 tile, A direct-to-reg =========
// 4 waves (2 row-slabs x 2 col-slabs). B double-buffered in LDS (32 KB).
// A loaded per-lane from global (wave-private rows), cvt f32->f16 in-reg.
__global__ __launch_bounds__(256, 3) void k2_mfma(const float* __restrict__ h_i,
                                                  const _Float16* __restrict__ W16t,
                                                  const float* __restrict__ c,
                                                  const float* __restrict__ u,
                                                  const int* __restrict__ sList,
                                                  const int* __restrict__ cntb,
                                                  float* __restrict__ y) {
    __shared__ _Float16 Blds[2][1024][8];     // 32 KB, unit = col*4+ks
    __shared__ float c_s[AA], u_s[AA];
    __shared__ float red[2][64];
    __shared__ int s_idx[64];

    const int t = blockIdx.x;
    int b = -1, ti = 0, base = 0;
    for (int bb = 0; bb < BB; ++bb) {
        int nt = (cntb[bb] + 63) >> 6;
        if (b < 0 && t < base + nt) { b = bb; ti = t - base; }
        base += nt;
    }
    if (b < 0) return;

    const int tid = threadIdx.x;
    const int lane = tid & 63;
    const int wave = tid >> 6;
    const int wr = wave >> 1;               // 0..1 -> 32-row slab
    const int wc = wave & 1;                // 0..1 -> 128-col slab

    if (tid < 64) s_idx[tid] = sList[b * SS + ti * 64 + tid];
    c_s[tid] = c[b * AA + tid];
    u_s[tid] = u[tid];
    __syncthreads();                         // s_idx ready

    const int kq = lane >> 4;
    const int lr = lane & 15;
    const int sb0 = __builtin_amdgcn_readfirstlane(wave * 256);
    _Float16* Bflat = &Blds[0][0][0];        // one buffer = 8192 halfs (16 KB)

    // per-lane A row pointers (frag rf=0: row wr*32+lr; rf=1: +16)
    const float* Arow0 = h_i + ((size_t)b * SS + s_idx[wr * 32 + lr]) * HH + kq * 8;
    const float* Arow1 = h_i + ((size_t)b * SS + s_idx[wr * 32 + 16 + lr]) * HH + kq * 8;

    f32x4 acc[2][8];
#pragma unroll
    for (int rf = 0; rf < 2; ++rf)
#pragma unroll
        for (int cf = 0; cf < 8; ++cf) acc[rf][cf] = (f32x4){0.f, 0.f, 0.f, 0.f};

    // ---- prologue: issue B(0) into buf 0; load A(0) into regs
    float4 a00, a01, a10, a11;
    {
#pragma unroll
        for (int i = 0; i < 4; ++i) {
            int sbase = sb0 + i * 64;
            async_lds16(W16t + (size_t)(sbase + lane) * 8,
                        Bflat + (size_t)sbase * 8);
        }
        a00 = *(const float4*)(Arow0);
        a01 = *(const float4*)(Arow0 + 4);
        a10 = *(const float4*)(Arow1);
        a11 = *(const float4*)(Arow1 + 4);
    }
    __syncthreads();                         // B(0) resident

    for (int t2 = 0; t2 < NT; ++t2) {
        const int cur = t2 & 1, nxt = cur ^ 1;
        const int k1 = (t2 + 1) * BK;
        float4 n00, n01, n10, n11;
        if (t2 < NT - 1) {
            // issue next B (async->LDS, 1KB contiguous per wave instr)
#pragma unroll
            for (int i = 0; i < 4; ++i) {
                int sbase = sb0 + i * 64;
                async_lds16(W16t + (size_t)(t2 + 1) * 8192 + (size_t)(sbase + lane) * 8,
                            Bflat + (size_t)nxt * 8192 + (size_t)sbase * 8);
            }
            // load next A into regs EARLY (hides HBM latency under MFMA)
            n00 = *(const float4*)(Arow0 + k1);
            n01 = *(const float4*)(Arow0 + k1 + 4);
            n10 = *(const float4*)(Arow1 + k1);
            n11 = *(const float4*)(Arow1 + k1 + 4);
        }

        half8 af[2], bf[8];
        af[0] = cvt8(a00, a01);
        af[1] = cvt8(a10, a11);
#pragma unroll
        for (int cf = 0; cf < 8; ++cf) {
            int col = wc * 128 + cf * 16 + lr;
            bf[cf] = *reinterpret_cast<half8*>(
                Bflat + (size_t)cur * 8192 + (size_t)(col * 4 + kq) * 8);
        }
#pragma unroll
        for (int rf = 0; rf < 2; ++rf)
#pragma unroll
            for (int cf = 0; cf < 8; ++cf)
                acc[rf][cf] = __builtin_amdgcn_mfma_f32_16x16x32_f16(
                    af[rf], bf[cf], acc[rf][cf], 0, 0, 0);

        if (t2 < NT - 1) { a00 = n00; a01 = n01; a10 = n10; a11 = n11; }
        __syncthreads();                     // B(nxt) resident, B(cur) free
    }

    // ---- epilogue: z += c[a]; y-row = sum_a tanh(z)*u[a]
#pragma unroll
    for (int rf = 0; rf < 2; ++rf) {
#pragma unroll
        for (int j = 0; j < 4; ++j) {
            float v = 0.f;
#pragma unroll
            for (int cf = 0; cf < 8; ++cf) {
                int col = wc * 128 + cf * 16 + lr;
                float z = acc[rf][cf][j] + c_s[col];
                v += tanhf(z) * u_s[col];
            }
            v += __shfl_xor(v, 1, 64);
            v += __shfl_xor(v, 2, 64);
            v += __shfl_xor(v, 4, 64);
            v += __shfl_xor(v, 8, 64);
            if (lr == 0) red[wc][wr * 32 + rf * 16 + kq * 4 + j] = v;
        }
    }
    __syncthreads();
    if (tid < 64) y[(size_t)b * SS + s_idx[tid]] = red[0][tid] + red[1][tid];
}

// ============ K34: fused row softmax stats + weighted chunk sum =============
__global__ __launch_bounds__(256) void k34(const float* __restrict__ h_i,
                                           const float* __restrict__ y,
                                           const int* __restrict__ mask,
                                           const int* __restrict__ pcnt,
                                           float* __restrict__ partial) {
    const int blk = blockIdx.x;
    const int b = blk >> 6;
    const int ch = blk & (CH - 1);
    const int tid = threadIdx.x;
    const int lane = tid & 63;
    const int wave = tid >> 6;
    __shared__ float rmax[4], rsum[4];
    __shared__ float aval[SCH];
    __shared__ int slist[SCH];
    __shared__ int mcnt;

    // row stats (recomputed per block; y/pcnt/mask rows are L2-resident)
    float beta[8];
    float mx = -INFINITY;
#pragma unroll
    for (int i = 0; i < 8; ++i) {
        int s = tid + i * 256;
        int p = pcnt[b * SS + s] - 1; if (p < 0) p = 0;
        float v = (mask[b * SS + s] != 0) ? y[(size_t)p * SS + s] : NEGV;
        beta[i] = v;
        mx = fmaxf(mx, v);
    }
    for (int off = 32; off; off >>= 1) mx = fmaxf(mx, __shfl_xor(mx, off, 64));
    if (lane == 0) rmax[wave] = mx;
    __syncthreads();
    mx = fmaxf(fmaxf(rmax[0], rmax[1]), fmaxf(rmax[2], rmax[3]));
    float sum = 0.f;
#pragma unroll
    for (int i = 0; i < 8; ++i) sum += expf(beta[i] - mx);
    for (int off = 32; off; off >>= 1) sum += __shfl_xor(sum, off, 64);
    if (lane == 0) rsum[wave] = sum;
    __syncthreads();
    sum = rsum[0] + rsum[1] + rsum[2] + rsum[3];
    const float inv = 1.f / sum;

    // this chunk's alphas + ballot compaction (skip alpha==0)
    float a = 0.f;
    bool nz = false;
    if (tid < SCH) {
        int s = ch * SCH + tid;
        if (mask[b * SS + s] != 0) {
            int p = pcnt[b * SS + s] - 1; if (p < 0) p = 0;
            a = expf(y[(size_t)p * SS + s] - mx) * inv;
            nz = (a != 0.f);
        }
    }
    unsigned long long mk = __ballot(nz);    // tid<32 all in wave 0
    if (tid < SCH) {
        int off = __popcll(mk & ((1ull << tid) - 1));
        if (nz) { slist[off] = tid; aval[off] = a; }
        if (tid == 0) mcnt = __popcll(mk);
    }
    __syncthreads();
    const int m = mcnt;
    const float* basep = h_i + (size_t)b * SS * HH + (size_t)ch * SCH * HH;
    f32x4 acc4 = {0.f, 0.f, 0.f, 0.f};
    for (int i2 = 0; i2 < m; ++i2) {
        float av = aval[i2];
        float4 v = *reinterpret_cast<const float4*>(
            &basep[(size_t)slist[i2] * HH + tid * 4]);
        acc4[0] += av * v.x; acc4[1] += av * v.y;
        acc4[2] += av * v.z; acc4[3] += av * v.w;
    }
    *reinterpret_cast<f32x4*>(&partial[(size_t)blk * HH + tid * 4]) = acc4;
}

// ============ K4b: out[b,h] = sum_ch partial[b,ch,h] ========================
__global__ __launch_bounds__(256) void k4b_reduce(const float* __restrict__ partial,
                                                  float* __restrict__ out) {
    int i = blockIdx.x * 256 + threadIdx.x;   // 0..32767
    int b = i >> 10, h = i & (HH - 1);
    float s = 0.f;
#pragma unroll
    for (int ch = 0; ch < CH; ++ch)
        s += partial[((size_t)(b * CH + ch)) * HH + h];
    out[i] = s;
}

extern "C" void kernel_launch(void* const* d_in, const int* in_sizes, int n_in,
                              void* d_out, int out_size, void* d_ws, size_t ws_size,
                              hipStream_t stream) {
    const float* h_i  = (const float*)d_in[0];
    const float* h_t  = (const float*)d_in[1];
    const int*   mask = (const int*)d_in[2];
    const float* W    = (const float*)d_in[3];
    const float* bias = (const float*)d_in[4];
    const float* u    = (const float*)d_in[5];
    float* out = (float*)d_out;

    float* c        = (float*)d_ws;                        // 8192
    float* y        = c + BB * AA;                         // 65536
    float* partial  = y + BB * SS;                         // B*CH*H = 2097152
    _Float16* W16t  = (_Float16*)(partial + BB * CH * HH); // 262144 f16
    int* sList      = (int*)(W16t + AA * HH);              // 65536
    int* cntb       = sList + BB * SS;                     // 32
    int* pcnt       = cntb + BB;                           // 65536

    k_prep<<<2208, 256, 0, stream>>>(W, h_t, bias, mask, W16t, c, sList, cntb, pcnt);
    k2_mfma<<<1024, 256, 0, stream>>>(h_i, W16t, c, u, sList, cntb, y);
    k34<<<BB * CH, 256, 0, stream>>>(h_i, y, mask, pcnt, partial);
    k4b_reduce<<<(BB * HH) / 256, 256, 0, stream>>>(partial, out);
}

// Round 12
// 120.173 us; speedup vs baseline: 1.1350x; 1.1350x over previous
//
#include <hip/hip_runtime.h>
#include <math.h>

#define BB 32
#define SS 2048
#define HH 1024
#define AA 256
#define NEGV (-1e20f)
#define BK 32
#define CH 64
#define SCH (SS / CH)   // 32
#define NT (HH / BK)    // 32

typedef _Float16 half8 __attribute__((ext_vector_type(8)));
typedef float f32x4 __attribute__((ext_vector_type(4)));

__device__ inline void async_lds16(const void* g, void* l) {
    __builtin_amdgcn_global_load_lds(
        (const __attribute__((address_space(1))) unsigned int*)g,
        (__attribute__((address_space(3))) unsigned int*)l, 16, 0, 0);
}

__device__ inline half8 cvt8(float4 a, float4 b) {
    half8 h;
    h[0] = (_Float16)a.x; h[1] = (_Float16)a.y;
    h[2] = (_Float16)a.z; h[3] = (_Float16)a.w;
    h[4] = (_Float16)b.x; h[5] = (_Float16)b.y;
    h[6] = (_Float16)b.z; h[7] = (_Float16)b.w;
    return h;
}

// ============ PREP ==========================================================
// blocks [0,128):    W1 -> f16, K-major 16KB tiles (tile kt: unit = col*4+ks)
// blocks [128,2176): c[b,a] = bias[a] + h_t[b,:].W[a,H:2H]
// blocks [2176,2208): per-b compact list {s: count[s]>b} (pad 64) + pcnt
__global__ __launch_bounds__(256) void k_prep(const float* __restrict__ W,
                                              const float* __restrict__ h_t,
                                              const float* __restrict__ bias,
                                              const int* __restrict__ mask,
                                              _Float16* __restrict__ W16t,
                                              float* __restrict__ c,
                                              int* __restrict__ sList,
                                              int* __restrict__ cntb,
                                              int* __restrict__ pcnt) {
    const int blk = blockIdx.x;
    const int tid = threadIdx.x;
    __shared__ int lcnt;

    if (blk < 128) {                        // ---- role A: W16 tiled cast
        int idx = blk * 256 + tid;          // unit id, < 32768
        int kt = idx >> 10;
        int u  = idx & 1023;
        int col = u >> 2, ks = u & 3;
        const float* src = W + (size_t)col * 2 * HH + kt * BK + ks * 8;
        float4 a0 = *(const float4*)src;
        float4 a1 = *(const float4*)(src + 4);
        *reinterpret_cast<half8*>(W16t + (size_t)idx * 8) = cvt8(a0, a1);
        return;
    }
    if (blk < 2176) {                       // ---- role B: ctx GEMV
        int wave = tid >> 6;
        int lane = tid & 63;
        int pair = (blk - 128) * 4 + wave;  // < B*A = 8192
        int b = pair >> 8;
        int a = pair & (AA - 1);
        const float* ht = h_t + (size_t)b * HH;
        const float* w2 = W + (size_t)a * 2 * HH + HH;
        float acc = 0.f;
        for (int k = lane; k < HH; k += 64)
            acc += ht[k] * w2[k];
        for (int off = 32; off; off >>= 1)
            acc += __shfl_down(acc, off, 64);
        if (lane == 0) c[pair] = acc + bias[a];
        return;
    }
    // ---- role C: compaction + prefix counts
    const int b = blk - 2176;
    if (tid == 0) lcnt = 0;
    __syncthreads();
    int* lst = sList + b * SS;
#pragma unroll
    for (int i = 0; i < 8; ++i) {
        int s = tid + i * 256;
        int pref = 0, tot = 0;
#pragma unroll
        for (int bb = 0; bb < BB; ++bb) {
            int mv = (mask[bb * SS + s] != 0);
            tot += mv;
            if (bb <= b) pref += mv;
        }
        pcnt[b * SS + s] = pref;
        if (tot > b) { int p = atomicAdd(&lcnt, 1); lst[p] = s; }
    }
    __syncthreads();
    const int m = lcnt;
    if (tid == 0) cntb[b] = m;
    if (m > 0) {
        int padded = (m + 63) & ~63;
        int first = lst[0];
        for (int j = m + tid; j < padded; j += 256) lst[j] = first;
    }
}

// ============ K2: MFMA f16 score GEMM, 64x256 tile (R10 form) ===============
// 4 waves (2 row-slabs x 2 col-slabs), A staged via LDS, B double-buffered.
__global__ __launch_bounds__(256, 2) void k2_mfma(const float* __restrict__ h_i,
                                                  const _Float16* __restrict__ W16t,
                                                  const float* __restrict__ c,
                                                  const float* __restrict__ u,
                                                  const int* __restrict__ sList,
                                                  const int* __restrict__ cntb,
                                                  float* __restrict__ y) {
    __shared__ _Float16 Alds[2][4][64][8];    // 8 KB
    __shared__ _Float16 Blds[2][1024][8];     // 32 KB, unit = col*4+ks
    __shared__ float c_s[AA], u_s[AA];
    __shared__ float red[2][64];
    __shared__ int s_idx[64];

    const int t = blockIdx.x;
    int b = -1, ti = 0, base = 0;
    for (int bb = 0; bb < BB; ++bb) {
        int nt = (cntb[bb] + 63) >> 6;
        if (b < 0 && t < base + nt) { b = bb; ti = t - base; }
        base += nt;
    }
    if (b < 0) return;

    const int tid = threadIdx.x;
    const int lane = tid & 63;
    const int wave = tid >> 6;
    const int wr = wave >> 1;               // 0..1 -> 32-row slab
    const int wc = wave & 1;                // 0..1 -> 128-col slab

    if (tid < 64) s_idx[tid] = sList[b * SS + ti * 64 + tid];
    c_s[tid] = c[b * AA + tid];
    u_s[tid] = u[tid];
    __syncthreads();

    f32x4 acc[2][8];
#pragma unroll
    for (int rf = 0; rf < 2; ++rf)
#pragma unroll
        for (int cf = 0; cf < 8; ++cf) acc[rf][cf] = (f32x4){0.f, 0.f, 0.f, 0.f};

    const int arow = tid >> 2;              // 0..63
    const int aks = tid & 3;                // 0..3
    const float* Abase = h_i + ((size_t)b * SS + s_idx[arow]) * HH + aks * 8;

    const int sb0 = __builtin_amdgcn_readfirstlane(wave * 256);
    _Float16* Bflat = &Blds[0][0][0];       // one buffer = 8192 halfs (16 KB)

    const int kq = lane >> 4;
    const int lr = lane & 15;

    // ---- prologue: stage K-tile 0 into buffer 0 (coalesced: tiled W16t)
    {
#pragma unroll
        for (int i = 0; i < 4; ++i) {
            int sbase = sb0 + i * 64;
            async_lds16(W16t + (size_t)(sbase + lane) * 8,
                        Bflat + (size_t)sbase * 8);
        }
        float4 v0 = *(const float4*)Abase;
        float4 v1 = *(const float4*)(Abase + 4);
        *reinterpret_cast<half8*>(&Alds[0][aks][arow][0]) = cvt8(v0, v1);
    }
    __syncthreads();

    for (int t2 = 0; t2 < NT; ++t2) {
        const int cur = t2 & 1, nxt = cur ^ 1;
        const int k1 = (t2 + 1) * BK;
        float4 v0, v1;
        if (t2 < NT - 1) {
            // issue next B (async->LDS, 1KB contiguous per wave instr) + next A
#pragma unroll
            for (int i = 0; i < 4; ++i) {
                int sbase = sb0 + i * 64;
                async_lds16(W16t + (size_t)(t2 + 1) * 8192 + (size_t)(sbase + lane) * 8,
                            Bflat + (size_t)nxt * 8192 + (size_t)sbase * 8);
            }
            v0 = *(const float4*)(Abase + k1);
            v1 = *(const float4*)(Abase + k1 + 4);
        }

        half8 af[2], bf[8];
#pragma unroll
        for (int rf = 0; rf < 2; ++rf)
            af[rf] = *reinterpret_cast<half8*>(&Alds[cur][kq][wr * 32 + rf * 16 + lr][0]);
#pragma unroll
        for (int cf = 0; cf < 8; ++cf) {
            int col = wc * 128 + cf * 16 + lr;
            bf[cf] = *reinterpret_cast<half8*>(
                Bflat + (size_t)cur * 8192 + (size_t)(col * 4 + kq) * 8);
        }
#pragma unroll
        for (int rf = 0; rf < 2; ++rf)
#pragma unroll
            for (int cf = 0; cf < 8; ++cf)
                acc[rf][cf] = __builtin_amdgcn_mfma_f32_16x16x32_f16(
                    af[rf], bf[cf], acc[rf][cf], 0, 0, 0);

        if (t2 < NT - 1) {
            *reinterpret_cast<half8*>(&Alds[nxt][aks][arow][0]) = cvt8(v0, v1);
        }
        __syncthreads();
    }

    // ---- epilogue: z += c[a]; y-row = sum_a tanh(z)*u[a]
#pragma unroll
    for (int rf = 0; rf < 2; ++rf) {
#pragma unroll
        for (int j = 0; j < 4; ++j) {
            float v = 0.f;
#pragma unroll
            for (int cf = 0; cf < 8; ++cf) {
                int col = wc * 128 + cf * 16 + lr;
                float z = acc[rf][cf][j] + c_s[col];
                v += tanhf(z) * u_s[col];
            }
            v += __shfl_xor(v, 1, 64);
            v += __shfl_xor(v, 2, 64);
            v += __shfl_xor(v, 4, 64);
            v += __shfl_xor(v, 8, 64);
            if (lr == 0) red[wc][wr * 32 + rf * 16 + kq * 4 + j] = v;
        }
    }
    __syncthreads();
    if (tid < 64) y[(size_t)b * SS + s_idx[tid]] = red[0][tid] + red[1][tid];
}

// ============ K34: row stats ONCE per block, then 4 weighted chunk sums =====
// grid = BB*16; block (b, grp) owns chunks grp*4 .. grp*4+3
__global__ __launch_bounds__(256) void k34(const float* __restrict__ h_i,
                                           const float* __restrict__ y,
                                           const int* __restrict__ mask,
                                           const int* __restrict__ pcnt,
                                           float* __restrict__ partial) {
    const int blk = blockIdx.x;
    const int b = blk >> 4;
    const int grp = blk & 15;
    const int tid = threadIdx.x;
    const int lane = tid & 63;
    const int wave = tid >> 6;
    __shared__ float rmax[4], rsum[4];
    __shared__ float aval[SCH];
    __shared__ int slist[SCH];
    __shared__ int mcnt;

    // ---- row stats, computed once (y/pcnt/mask are L2-resident)
    float beta[8];
    float mx = -INFINITY;
#pragma unroll
    for (int i = 0; i < 8; ++i) {
        int s = tid + i * 256;
        int p = pcnt[b * SS + s] - 1; if (p < 0) p = 0;
        float v = (mask[b * SS + s] != 0) ? y[(size_t)p * SS + s] : NEGV;
        beta[i] = v;
        mx = fmaxf(mx, v);
    }
    for (int off = 32; off; off >>= 1) mx = fmaxf(mx, __shfl_xor(mx, off, 64));
    if (lane == 0) rmax[wave] = mx;
    __syncthreads();
    mx = fmaxf(fmaxf(rmax[0], rmax[1]), fmaxf(rmax[2], rmax[3]));
    float sum = 0.f;
#pragma unroll
    for (int i = 0; i < 8; ++i) sum += expf(beta[i] - mx);
    for (int off = 32; off; off >>= 1) sum += __shfl_xor(sum, off, 64);
    if (lane == 0) rsum[wave] = sum;
    __syncthreads();
    sum = rsum[0] + rsum[1] + rsum[2] + rsum[3];
    const float inv = 1.f / sum;

    // ---- 4 chunks: alpha (32 wide) + ballot compact + weighted h_i sum
    for (int cc = 0; cc < 4; ++cc) {
        const int ch = grp * 4 + cc;
        float a = 0.f;
        bool nz = false;
        if (tid < SCH) {
            int s = ch * SCH + tid;
            if (mask[b * SS + s] != 0) {
                int p = pcnt[b * SS + s] - 1; if (p < 0) p = 0;
                a = expf(y[(size_t)p * SS + s] - mx) * inv;
                nz = (a != 0.f);
            }
        }
        unsigned long long mk = __ballot(nz);    // tid<32 all in wave 0
        if (tid < SCH) {
            int off = __popcll(mk & ((1ull << tid) - 1));
            if (nz) { slist[off] = tid; aval[off] = a; }
            if (tid == 0) mcnt = __popcll(mk);
        }
        __syncthreads();
        const int m = mcnt;
        const float* basep = h_i + (size_t)b * SS * HH + (size_t)ch * SCH * HH;
        f32x4 acc4 = {0.f, 0.f, 0.f, 0.f};
        for (int i2 = 0; i2 < m; ++i2) {
            float av = aval[i2];
            float4 v = *reinterpret_cast<const float4*>(
                &basep[(size_t)slist[i2] * HH + tid * 4]);
            acc4[0] += av * v.x; acc4[1] += av * v.y;
            acc4[2] += av * v.z; acc4[3] += av * v.w;
        }
        *reinterpret_cast<f32x4*>(
            &partial[((size_t)(b * CH + ch)) * HH + tid * 4]) = acc4;
        __syncthreads();   // aval/slist/mcnt reused next chunk
    }
}

// ============ K4b: out[b,h] = sum_ch partial[b,ch,h] ========================
__global__ __launch_bounds__(256) void k4b_reduce(const float* __restrict__ partial,
                                                  float* __restrict__ out) {
    int i = blockIdx.x * 256 + threadIdx.x;   // 0..32767
    int b = i >> 10, h = i & (HH - 1);
    float s = 0.f;
#pragma unroll
    for (int ch = 0; ch < CH; ++ch)
        s += partial[((size_t)(b * CH + ch)) * HH + h];
    out[i] = s;
}

extern "C" void kernel_launch(void* const* d_in, const int* in_sizes, int n_in,
                              void* d_out, int out_size, void* d_ws, size_t ws_size,
                              hipStream_t stream) {
    const float* h_i  = (const float*)d_in[0];
    const float* h_t  = (const float*)d_in[1];
    const int*   mask = (const int*)d_in[2];
    const float* W    = (const float*)d_in[3];
    const float* bias = (const float*)d_in[4];
    const float* u    = (const float*)d_in[5];
    float* out = (float*)d_out;

    float* c        = (float*)d_ws;                        // 8192
    float* y        = c + BB * AA;                         // 65536
    float* partial  = y + BB * SS;                         // B*CH*H = 2097152
    _Float16* W16t  = (_Float16*)(partial + BB * CH * HH); // 262144 f16
    int* sList      = (int*)(W16t + AA * HH);              // 65536
    int* cntb       = sList + BB * SS;                     // 32
    int* pcnt       = cntb + BB;                           // 65536

    k_prep<<<2208, 256, 0, stream>>>(W, h_t, bias, mask, W16t, c, sList, cntb, pcnt);
    k2_mfma<<<1024, 256, 0, stream>>>(h_i, W16t, c, u, sList, cntb, y);
    k34<<<BB * 16, 256, 0, stream>>>(h_i, y, mask, pcnt, partial);
    k4b_reduce<<<(BB * HH) / 256, 256, 0, stream>>>(partial, out);
}

// Round 13
// 112.344 us; speedup vs baseline: 1.2141x; 1.0697x over previous
//
#include <hip/hip_runtime.h>
#include <math.h>

#define BB 32
#define SS 2048
#define HH 1024
#define AA 256
#define NEGV (-1e20f)
#define BK 32
#define CH 64
#define SCH (SS / CH)   // 32
#define NT (HH / BK)    // 32

typedef _Float16 half8 __attribute__((ext_vector_type(8)));
typedef float f32x4 __attribute__((ext_vector_type(4)));

__device__ inline void async_lds16(const void* g, void* l) {
    __builtin_amdgcn_global_load_lds(
        (const __attribute__((address_space(1))) unsigned int*)g,
        (__attribute__((address_space(3))) unsigned int*)l, 16, 0, 0);
}

__device__ inline f32x4 gload4(const float* p) {
    f32x4 r;
    asm volatile("global_load_dwordx4 %0, %1, off"
                 : "=&v"(r) : "v"(p) : "memory");
    return r;
}

__device__ inline half8 cvt8(f32x4 a, f32x4 b) {
    half8 h;
    h[0] = (_Float16)a[0]; h[1] = (_Float16)a[1];
    h[2] = (_Float16)a[2]; h[3] = (_Float16)a[3];
    h[4] = (_Float16)b[0]; h[5] = (_Float16)b[1];
    h[6] = (_Float16)b[2]; h[7] = (_Float16)b[3];
    return h;
}
__device__ inline half8 cvt8f(float4 a, float4 b) {
    half8 h;
    h[0] = (_Float16)a.x; h[1] = (_Float16)a.y;
    h[2] = (_Float16)a.z; h[3] = (_Float16)a.w;
    h[4] = (_Float16)b.x; h[5] = (_Float16)b.y;
    h[6] = (_Float16)b.z; h[7] = (_Float16)b.w;
    return h;
}

// ============ PREP ==========================================================
__global__ __launch_bounds__(256) void k_prep(const float* __restrict__ W,
                                              const float* __restrict__ h_t,
                                              const float* __restrict__ bias,
                                              const int* __restrict__ mask,
                                              _Float16* __restrict__ W16t,
                                              float* __restrict__ c,
                                              int* __restrict__ sList,
                                              int* __restrict__ cntb,
                                              int* __restrict__ pcnt) {
    const int blk = blockIdx.x;
    const int tid = threadIdx.x;
    __shared__ int lcnt;

    if (blk < 128) {                        // ---- role A: W16 tiled cast
        int idx = blk * 256 + tid;          // unit id, < 32768
        int kt = idx >> 10;
        int u  = idx & 1023;
        int col = u >> 2, ks = u & 3;
        const float* src = W + (size_t)col * 2 * HH + kt * BK + ks * 8;
        float4 a0 = *(const float4*)src;
        float4 a1 = *(const float4*)(src + 4);
        *reinterpret_cast<half8*>(W16t + (size_t)idx * 8) = cvt8f(a0, a1);
        return;
    }
    if (blk < 2176) {                       // ---- role B: ctx GEMV
        int wave = tid >> 6;
        int lane = tid & 63;
        int pair = (blk - 128) * 4 + wave;  // < B*A = 8192
        int b = pair >> 8;
        int a = pair & (AA - 1);
        const float* ht = h_t + (size_t)b * HH;
        const float* w2 = W + (size_t)a * 2 * HH + HH;
        float acc = 0.f;
        for (int k = lane; k < HH; k += 64)
            acc += ht[k] * w2[k];
        for (int off = 32; off; off >>= 1)
            acc += __shfl_down(acc, off, 64);
        if (lane == 0) c[pair] = acc + bias[a];
        return;
    }
    // ---- role C: compaction (wave-ballot, unordered) + prefix counts
    const int b = blk - 2176;
    const int lane = tid & 63;
    if (tid == 0) lcnt = 0;
    __syncthreads();
    int* lst = sList + b * SS;
#pragma unroll
    for (int i = 0; i < 8; ++i) {
        int s = tid + i * 256;
        int pref = 0, tot = 0;
#pragma unroll
        for (int bb = 0; bb < BB; ++bb) {
            int mv = (mask[bb * SS + s] != 0);
            tot += mv;
            if (bb <= b) pref += mv;
        }
        pcnt[b * SS + s] = pref;
        bool need = (tot > b);
        unsigned long long mk = __ballot(need);
        int wbase = 0;
        if (lane == 0) wbase = atomicAdd(&lcnt, __popcll(mk));
        wbase = __shfl(wbase, 0, 64);
        if (need) lst[wbase + __popcll(mk & ((1ull << lane) - 1))] = s;
    }
    __syncthreads();
    const int m = lcnt;
    if (tid == 0) cntb[b] = m;
    if (m > 0) {
        int padded = (m + 63) & ~63;
        int first = lst[0];
        for (int j = m + tid; j < padded; j += 256) lst[j] = first;
    }
}

// ============ K2: MFMA f16 score GEMM, 64x256 tile ==========================
// A: reg prefetch -> LDS TRIPLE buffer (write 2 steps ahead of read).
// B: dma double buffer (L2-resident W16t). Raw s_barrier + counted vmcnt so
// A-prefetch loads stay in flight across barriers (T3/T4).
__global__ __launch_bounds__(256, 3) void k2_mfma(const float* __restrict__ h_i,
                                                  const _Float16* __restrict__ W16t,
                                                  const float* __restrict__ c,
                                                  const float* __restrict__ u,
                                                  const int* __restrict__ sList,
                                                  const int* __restrict__ cntb,
                                                  float* __restrict__ y) {
    __shared__ _Float16 Alds[3][4][64][8];    // 12 KB (triple)
    __shared__ _Float16 Blds[2][1024][8];     // 32 KB, unit = col*4+ks
    __shared__ float c_s[AA], u_s[AA];
    __shared__ float red[2][64];
    __shared__ int s_idx[64];

    const int t = blockIdx.x;
    int b = -1, ti = 0, base = 0;
    for (int bb = 0; bb < BB; ++bb) {
        int nt = (cntb[bb] + 63) >> 6;
        if (b < 0 && t < base + nt) { b = bb; ti = t - base; }
        base += nt;
    }
    if (b < 0) return;

    const int tid = threadIdx.x;
    const int lane = tid & 63;
    const int wave = tid >> 6;
    const int wr = wave >> 1;               // 0..1 -> 32-row slab
    const int wc = wave & 1;                // 0..1 -> 128-col slab

    if (tid < 64) s_idx[tid] = sList[b * SS + ti * 64 + tid];
    c_s[tid] = c[b * AA + tid];
    u_s[tid] = u[tid];
    __syncthreads();        // full drain: clean vmcnt state for manual counting

    f32x4 acc[2][8];
#pragma unroll
    for (int rf = 0; rf < 2; ++rf)
#pragma unroll
        for (int cf = 0; cf < 8; ++cf) acc[rf][cf] = (f32x4){0.f, 0.f, 0.f, 0.f};

    const int arow = tid >> 2;              // 0..63
    const int aks = tid & 3;                // 0..3
    const float* Abase = h_i + ((size_t)b * SS + s_idx[arow]) * HH + aks * 8;

    const int sb0 = __builtin_amdgcn_readfirstlane(wave * 256);
    _Float16* Bflat = &Blds[0][0][0];       // one buffer = 8192 halfs (16 KB)

    const int kq = lane >> 4;
    const int lr = lane & 15;

    // ---- prologue. Issue order (per wave, pinned by volatile ordering):
    //   A(0)x2, A(1)x2, B(0)x4, A(2)x2   -> 10 outstanding
    f32x4 r0a = gload4(Abase);
    f32x4 r0b = gload4(Abase + 4);
    f32x4 r1a = gload4(Abase + BK);
    f32x4 r1b = gload4(Abase + BK + 4);
#pragma unroll
    for (int i = 0; i < 4; ++i) {
        int sbase = sb0 + i * 64;
        async_lds16(W16t + (size_t)(sbase + lane) * 8, Bflat + (size_t)sbase * 8);
    }
    f32x4 rAa = gload4(Abase + 2 * BK);
    f32x4 rAb = gload4(Abase + 2 * BK + 4);

    asm volatile("s_waitcnt vmcnt(6)" ::: "memory");   // A(0),A(1) ready
    __builtin_amdgcn_sched_barrier(0);
    *reinterpret_cast<half8*>(&Alds[0][aks][arow][0]) = cvt8(r0a, r0b);
    *reinterpret_cast<half8*>(&Alds[1][aks][arow][0]) = cvt8(r1a, r1b);
    asm volatile("s_waitcnt vmcnt(2) lgkmcnt(0)" ::: "memory");  // B(0) done; A(2) in flight
    __builtin_amdgcn_sched_barrier(0);
    __builtin_amdgcn_s_barrier();

    for (int t2 = 0; t2 < NT; ++t2) {
        const int cur3 = t2 % 3, curB = t2 & 1;
        // 1. issue B(t+1) dma (4 ops)
        if (t2 + 1 < NT) {
#pragma unroll
            for (int i = 0; i < 4; ++i) {
                int sbase = sb0 + i * 64;
                async_lds16(W16t + (size_t)(t2 + 1) * 8192 + (size_t)(sbase + lane) * 8,
                            Bflat + (size_t)((t2 + 1) & 1) * 8192 + (size_t)sbase * 8);
            }
        }
        // 2. consume rA = A(t+2): drain A loads, keep this step's 4 B-dma
        if (t2 + 2 < NT) {
            asm volatile("s_waitcnt vmcnt(4)" ::: "memory");
            __builtin_amdgcn_sched_barrier(0);
            *reinterpret_cast<half8*>(&Alds[(t2 + 2) % 3][aks][arow][0]) = cvt8(rAa, rAb);
        }
        // 3. issue A(t+3) (2 ops) — stays in flight across the barrier
        if (t2 + 3 < NT) {
            rAa = gload4(Abase + (t2 + 3) * BK);
            rAb = gload4(Abase + (t2 + 3) * BK + 4);
        }
        // 4. fragments + MFMA (compiler handles lgkm waits for ds_reads)
        half8 af[2], bf[8];
#pragma unroll
        for (int rf = 0; rf < 2; ++rf)
            af[rf] = *reinterpret_cast<half8*>(&Alds[cur3][kq][wr * 32 + rf * 16 + lr][0]);
#pragma unroll
        for (int cf = 0; cf < 8; ++cf) {
            int col = wc * 128 + cf * 16 + lr;
            bf[cf] = *reinterpret_cast<half8*>(
                Bflat + (size_t)curB * 8192 + (size_t)(col * 4 + kq) * 8);
        }
#pragma unroll
        for (int rf = 0; rf < 2; ++rf)
#pragma unroll
            for (int cf = 0; cf < 8; ++cf)
                acc[rf][cf] = __builtin_amdgcn_mfma_f32_16x16x32_f16(
                    af[rf], bf[cf], acc[rf][cf], 0, 0, 0);
        // 5. barrier: B(t+1) must be resident; A(t+3) may stay in flight
        if (t2 < NT - 1) {
            if (t2 + 3 < NT)
                asm volatile("s_waitcnt vmcnt(2) lgkmcnt(0)" ::: "memory");
            else
                asm volatile("s_waitcnt vmcnt(0) lgkmcnt(0)" ::: "memory");
            __builtin_amdgcn_sched_barrier(0);
            __builtin_amdgcn_s_barrier();
        }
    }

    // ---- epilogue: z += c[a]; y-row = sum_a tanh(z)*u[a]
#pragma unroll
    for (int rf = 0; rf < 2; ++rf) {
#pragma unroll
        for (int j = 0; j < 4; ++j) {
            float v = 0.f;
#pragma unroll
            for (int cf = 0; cf < 8; ++cf) {
                int col = wc * 128 + cf * 16 + lr;
                float z = acc[rf][cf][j] + c_s[col];
                v += tanhf(z) * u_s[col];
            }
            v += __shfl_xor(v, 1, 64);
            v += __shfl_xor(v, 2, 64);
            v += __shfl_xor(v, 4, 64);
            v += __shfl_xor(v, 8, 64);
            if (lr == 0) red[wc][wr * 32 + rf * 16 + kq * 4 + j] = v;
        }
    }
    __syncthreads();
    if (tid < 64) y[(size_t)b * SS + s_idx[tid]] = red[0][tid] + red[1][tid];
}

// ============ K34: row stats once per block, then 4 weighted chunk sums =====
__global__ __launch_bounds__(256) void k34(const float* __restrict__ h_i,
                                           const float* __restrict__ y,
                                           const int* __restrict__ mask,
                                           const int* __restrict__ pcnt,
                                           float* __restrict__ partial) {
    const int blk = blockIdx.x;
    const int b = blk >> 4;
    const int grp = blk & 15;
    const int tid = threadIdx.x;
    const int lane = tid & 63;
    const int wave = tid >> 6;
    __shared__ float rmax[4], rsum[4];
    __shared__ float aval[SCH];
    __shared__ int slist[SCH];
    __shared__ int mcnt;

    float beta[8];
    float mx = -INFINITY;
#pragma unroll
    for (int i = 0; i < 8; ++i) {
        int s = tid + i * 256;
        int p = pcnt[b * SS + s] - 1; if (p < 0) p = 0;
        float v = (mask[b * SS + s] != 0) ? y[(size_t)p * SS + s] : NEGV;
        beta[i] = v;
        mx = fmaxf(mx, v);
    }
    for (int off = 32; off; off >>= 1) mx = fmaxf(mx, __shfl_xor(mx, off, 64));
    if (lane == 0) rmax[wave] = mx;
    __syncthreads();
    mx = fmaxf(fmaxf(rmax[0], rmax[1]), fmaxf(rmax[2], rmax[3]));
    float sum = 0.f;
#pragma unroll
    for (int i = 0; i < 8; ++i) sum += expf(beta[i] - mx);
    for (int off = 32; off; off >>= 1) sum += __shfl_xor(sum, off, 64);
    if (lane == 0) rsum[wave] = sum;
    __syncthreads();
    sum = rsum[0] + rsum[1] + rsum[2] + rsum[3];
    const float inv = 1.f / sum;

    for (int cc = 0; cc < 4; ++cc) {
        const int ch = grp * 4 + cc;
        float a = 0.f;
        bool nz = false;
        if (tid < SCH) {
            int s = ch * SCH + tid;
            if (mask[b * SS + s] != 0) {
                int p = pcnt[b * SS + s] - 1; if (p < 0) p = 0;
                a = expf(y[(size_t)p * SS + s] - mx) * inv;
                nz = (a != 0.f);
            }
        }
        unsigned long long mk = __ballot(nz);
        if (tid < SCH) {
            int off = __popcll(mk & ((1ull << tid) - 1));
            if (nz) { slist[off] = tid; aval[off] = a; }
            if (tid == 0) mcnt = __popcll(mk);
        }
        __syncthreads();
        const int m = mcnt;
        const float* basep = h_i + (size_t)b * SS * HH + (size_t)ch * SCH * HH;
        f32x4 acc4 = {0.f, 0.f, 0.f, 0.f};
        for (int i2 = 0; i2 < m; ++i2) {
            float av = aval[i2];
            float4 v = *reinterpret_cast<const float4*>(
                &basep[(size_t)slist[i2] * HH + tid * 4]);
            acc4[0] += av * v.x; acc4[1] += av * v.y;
            acc4[2] += av * v.z; acc4[3] += av * v.w;
        }
        *reinterpret_cast<f32x4*>(
            &partial[((size_t)(b * CH + ch)) * HH + tid * 4]) = acc4;
        __syncthreads();
    }
}

// ============ K4b ===========================================================
__global__ __launch_bounds__(256) void k4b_reduce(const float* __restrict__ partial,
                                                  float* __restrict__ out) {
    int i = blockIdx.x * 256 + threadIdx.x;   // 0..32767
    int b = i >> 10, h = i & (HH - 1);
    float s = 0.f;
#pragma unroll
    for (int ch = 0; ch < CH; ++ch)
        s += partial[((size_t)(b * CH + ch)) * HH + h];
    out[i] = s;
}

extern "C" void kernel_launch(void* const* d_in, const int* in_sizes, int n_in,
                              void* d_out, int out_size, void* d_ws, size_t ws_size,
                              hipStream_t stream) {
    const float* h_i  = (const float*)d_in[0];
    const float* h_t  = (const float*)d_in[1];
    const int*   mask = (const int*)d_in[2];
    const float* W    = (const float*)d_in[3];
    const float* bias = (const float*)d_in[4];
    const float* u    = (const float*)d_in[5];
    float* out = (float*)d_out;

    float* c        = (float*)d_ws;                        // 8192
    float* y        = c + BB * AA;                         // 65536
    float* partial  = y + BB * SS;                         // B*CH*H = 2097152
    _Float16* W16t  = (_Float16*)(partial + BB * CH * HH); // 262144 f16
    int* sList      = (int*)(W16t + AA * HH);              // 65536
    int* cntb       = sList + BB * SS;                     // 32
    int* pcnt       = cntb + BB;                           // 65536

    k_prep<<<2208, 256, 0, stream>>>(W, h_t, bias, mask, W16t, c, sList, cntb, pcnt);
    k2_mfma<<<1024, 256, 0, stream>>>(h_i, W16t, c, u, sList, cntb, y);
    k34<<<BB * 16, 256, 0, stream>>>(h_i, y, mask, pcnt, partial);
    k4b_reduce<<<(BB * HH) / 256, 256, 0, stream>>>(partial, out);
}

// Round 14
// 97.021 us; speedup vs baseline: 1.4059x; 1.1579x over previous
//
#include <hip/hip_runtime.h>
#include <math.h>

#define BB 32
#define SS 2048
#define HH 1024
#define AA 256
#define NEGV (-1e20f)
#define BK 32
#define NT (HH / BK)    // 32
#define NG 16           // k34 groups per batch; each owns 128 rows

typedef _Float16 half8 __attribute__((ext_vector_type(8)));
typedef float f32x4 __attribute__((ext_vector_type(4)));

__device__ inline void async_lds16(const void* g, void* l) {
    __builtin_amdgcn_global_load_lds(
        (const __attribute__((address_space(1))) unsigned int*)g,
        (__attribute__((address_space(3))) unsigned int*)l, 16, 0, 0);
}

__device__ inline f32x4 gload4(const float* p) {
    f32x4 r;
    asm volatile("global_load_dwordx4 %0, %1, off"
                 : "=&v"(r) : "v"(p) : "memory");
    return r;
}

__device__ inline half8 cvt8(f32x4 a, f32x4 b) {
    half8 h;
    h[0] = (_Float16)a[0]; h[1] = (_Float16)a[1];
    h[2] = (_Float16)a[2]; h[3] = (_Float16)a[3];
    h[4] = (_Float16)b[0]; h[5] = (_Float16)b[1];
    h[6] = (_Float16)b[2]; h[7] = (_Float16)b[3];
    return h;
}
__device__ inline half8 cvt8f(float4 a, float4 b) {
    half8 h;
    h[0] = (_Float16)a.x; h[1] = (_Float16)a.y;
    h[2] = (_Float16)a.z; h[3] = (_Float16)a.w;
    h[4] = (_Float16)b.x; h[5] = (_Float16)b.y;
    h[6] = (_Float16)b.z; h[7] = (_Float16)b.w;
    return h;
}

// ============ PREP ==========================================================
__global__ __launch_bounds__(256) void k_prep(const float* __restrict__ W,
                                              const float* __restrict__ h_t,
                                              const float* __restrict__ bias,
                                              const int* __restrict__ mask,
                                              _Float16* __restrict__ W16t,
                                              float* __restrict__ c,
                                              int* __restrict__ sList,
                                              int* __restrict__ cntb,
                                              int* __restrict__ pcnt) {
    const int blk = blockIdx.x;
    const int tid = threadIdx.x;
    __shared__ int lcnt;

    if (blk < 128) {                        // ---- role A: W16 tiled cast
        int idx = blk * 256 + tid;          // unit id, < 32768
        int kt = idx >> 10;
        int u  = idx & 1023;
        int col = u >> 2, ks = u & 3;
        const float* src = W + (size_t)col * 2 * HH + kt * BK + ks * 8;
        float4 a0 = *(const float4*)src;
        float4 a1 = *(const float4*)(src + 4);
        *reinterpret_cast<half8*>(W16t + (size_t)idx * 8) = cvt8f(a0, a1);
        return;
    }
    if (blk < 2176) {                       // ---- role B: ctx GEMV
        int wave = tid >> 6;
        int lane = tid & 63;
        int pair = (blk - 128) * 4 + wave;  // < B*A = 8192
        int b = pair >> 8;
        int a = pair & (AA - 1);
        const float* ht = h_t + (size_t)b * HH;
        const float* w2 = W + (size_t)a * 2 * HH + HH;
        float acc = 0.f;
        for (int k = lane; k < HH; k += 64)
            acc += ht[k] * w2[k];
        for (int off = 32; off; off >>= 1)
            acc += __shfl_down(acc, off, 64);
        if (lane == 0) c[pair] = acc + bias[a];
        return;
    }
    // ---- role C: compaction (wave-ballot, unordered) + prefix counts
    const int b = blk - 2176;
    const int lane = tid & 63;
    if (tid == 0) lcnt = 0;
    __syncthreads();
    int* lst = sList + b * SS;
#pragma unroll
    for (int i = 0; i < 8; ++i) {
        int s = tid + i * 256;
        int pref = 0, tot = 0;
#pragma unroll
        for (int bb = 0; bb < BB; ++bb) {
            int mv = (mask[bb * SS + s] != 0);
            tot += mv;
            if (bb <= b) pref += mv;
        }
        pcnt[b * SS + s] = pref;
        bool need = (tot > b);
        unsigned long long mk = __ballot(need);
        int wbase = 0;
        if (lane == 0) wbase = atomicAdd(&lcnt, __popcll(mk));
        wbase = __shfl(wbase, 0, 64);
        if (need) lst[wbase + __popcll(mk & ((1ull << lane) - 1))] = s;
    }
    __syncthreads();
    const int m = lcnt;
    if (tid == 0) cntb[b] = m;
    if (m > 0) {
        int padded = (m + 63) & ~63;
        int first = lst[0];
        for (int j = m + tid; j < padded; j += 256) lst[j] = first;
    }
}

// ============ K2: MFMA f16 score GEMM, 64x256 tile (R13 pipelined form) =====
__global__ __launch_bounds__(256, 3) void k2_mfma(const float* __restrict__ h_i,
                                                  const _Float16* __restrict__ W16t,
                                                  const float* __restrict__ c,
                                                  const float* __restrict__ u,
                                                  const int* __restrict__ sList,
                                                  const int* __restrict__ cntb,
                                                  float* __restrict__ y) {
    __shared__ _Float16 Alds[3][4][64][8];    // 12 KB (triple)
    __shared__ _Float16 Blds[2][1024][8];     // 32 KB, unit = col*4+ks
    __shared__ float c_s[AA], u_s[AA];
    __shared__ float red[2][64];
    __shared__ int s_idx[64];

    const int t = blockIdx.x;
    int b = -1, ti = 0, base = 0;
    for (int bb = 0; bb < BB; ++bb) {
        int nt = (cntb[bb] + 63) >> 6;
        if (b < 0 && t < base + nt) { b = bb; ti = t - base; }
        base += nt;
    }
    if (b < 0) return;

    const int tid = threadIdx.x;
    const int lane = tid & 63;
    const int wave = tid >> 6;
    const int wr = wave >> 1;               // 0..1 -> 32-row slab
    const int wc = wave & 1;                // 0..1 -> 128-col slab

    if (tid < 64) s_idx[tid] = sList[b * SS + ti * 64 + tid];
    c_s[tid] = c[b * AA + tid];
    u_s[tid] = u[tid];
    __syncthreads();        // full drain: clean vmcnt state for manual counting

    f32x4 acc[2][8];
#pragma unroll
    for (int rf = 0; rf < 2; ++rf)
#pragma unroll
        for (int cf = 0; cf < 8; ++cf) acc[rf][cf] = (f32x4){0.f, 0.f, 0.f, 0.f};

    const int arow = tid >> 2;              // 0..63
    const int aks = tid & 3;                // 0..3
    const float* Abase = h_i + ((size_t)b * SS + s_idx[arow]) * HH + aks * 8;

    const int sb0 = __builtin_amdgcn_readfirstlane(wave * 256);
    _Float16* Bflat = &Blds[0][0][0];       // one buffer = 8192 halfs (16 KB)

    const int kq = lane >> 4;
    const int lr = lane & 15;

    // ---- prologue: A(0)x2, A(1)x2, B(0)x4, A(2)x2 -> 10 outstanding
    f32x4 r0a = gload4(Abase);
    f32x4 r0b = gload4(Abase + 4);
    f32x4 r1a = gload4(Abase + BK);
    f32x4 r1b = gload4(Abase + BK + 4);
#pragma unroll
    for (int i = 0; i < 4; ++i) {
        int sbase = sb0 + i * 64;
        async_lds16(W16t + (size_t)(sbase + lane) * 8, Bflat + (size_t)sbase * 8);
    }
    f32x4 rAa = gload4(Abase + 2 * BK);
    f32x4 rAb = gload4(Abase + 2 * BK + 4);

    asm volatile("s_waitcnt vmcnt(6)" ::: "memory");   // A(0),A(1) ready
    __builtin_amdgcn_sched_barrier(0);
    *reinterpret_cast<half8*>(&Alds[0][aks][arow][0]) = cvt8(r0a, r0b);
    *reinterpret_cast<half8*>(&Alds[1][aks][arow][0]) = cvt8(r1a, r1b);
    asm volatile("s_waitcnt vmcnt(2) lgkmcnt(0)" ::: "memory");  // B(0) done
    __builtin_amdgcn_sched_barrier(0);
    __builtin_amdgcn_s_barrier();

    for (int t2 = 0; t2 < NT; ++t2) {
        const int cur3 = t2 % 3, curB = t2 & 1;
        if (t2 + 1 < NT) {
#pragma unroll
            for (int i = 0; i < 4; ++i) {
                int sbase = sb0 + i * 64;
                async_lds16(W16t + (size_t)(t2 + 1) * 8192 + (size_t)(sbase + lane) * 8,
                            Bflat + (size_t)((t2 + 1) & 1) * 8192 + (size_t)sbase * 8);
            }
        }
        if (t2 + 2 < NT) {
            asm volatile("s_waitcnt vmcnt(4)" ::: "memory");
            __builtin_amdgcn_sched_barrier(0);
            *reinterpret_cast<half8*>(&Alds[(t2 + 2) % 3][aks][arow][0]) = cvt8(rAa, rAb);
        }
        if (t2 + 3 < NT) {
            rAa = gload4(Abase + (t2 + 3) * BK);
            rAb = gload4(Abase + (t2 + 3) * BK + 4);
        }
        half8 af[2], bf[8];
#pragma unroll
        for (int rf = 0; rf < 2; ++rf)
            af[rf] = *reinterpret_cast<half8*>(&Alds[cur3][kq][wr * 32 + rf * 16 + lr][0]);
#pragma unroll
        for (int cf = 0; cf < 8; ++cf) {
            int col = wc * 128 + cf * 16 + lr;
            bf[cf] = *reinterpret_cast<half8*>(
                Bflat + (size_t)curB * 8192 + (size_t)(col * 4 + kq) * 8);
        }
#pragma unroll
        for (int rf = 0; rf < 2; ++rf)
#pragma unroll
            for (int cf = 0; cf < 8; ++cf)
                acc[rf][cf] = __builtin_amdgcn_mfma_f32_16x16x32_f16(
                    af[rf], bf[cf], acc[rf][cf], 0, 0, 0);
        if (t2 < NT - 1) {
            if (t2 + 3 < NT)
                asm volatile("s_waitcnt vmcnt(2) lgkmcnt(0)" ::: "memory");
            else
                asm volatile("s_waitcnt vmcnt(0) lgkmcnt(0)" ::: "memory");
            __builtin_amdgcn_sched_barrier(0);
            __builtin_amdgcn_s_barrier();
        }
    }

    // ---- epilogue
#pragma unroll
    for (int rf = 0; rf < 2; ++rf) {
#pragma unroll
        for (int j = 0; j < 4; ++j) {
            float v = 0.f;
#pragma unroll
            for (int cf = 0; cf < 8; ++cf) {
                int col = wc * 128 + cf * 16 + lr;
                float z = acc[rf][cf][j] + c_s[col];
                v += tanhf(z) * u_s[col];
            }
            v += __shfl_xor(v, 1, 64);
            v += __shfl_xor(v, 2, 64);
            v += __shfl_xor(v, 4, 64);
            v += __shfl_xor(v, 8, 64);
            if (lr == 0) red[wc][wr * 32 + rf * 16 + kq * 4 + j] = v;
        }
    }
    __syncthreads();
    if (tid < 64) y[(size_t)b * SS + s_idx[tid]] = red[0][tid] + red[1][tid];
}

// ============ K34: stats once; combined 128-row compact list; unroll-4 ======
// grid = BB*NG; block (b,grp) owns rows grp*128 .. grp*128+127, one partial.
__global__ __launch_bounds__(256) void k34(const float* __restrict__ h_i,
                                           const float* __restrict__ y,
                                           const int* __restrict__ mask,
                                           const int* __restrict__ pcnt,
                                           float* __restrict__ partial) {
    const int blk = blockIdx.x;
    const int b = blk >> 4;
    const int grp = blk & (NG - 1);
    const int tid = threadIdx.x;
    const int lane = tid & 63;
    const int wave = tid >> 6;
    __shared__ float rmax[4], rsum[4];
    __shared__ float aval[128];
    __shared__ int slist[128];
    __shared__ int mtot;

    // ---- row stats, once
    float beta[8];
    float mx = -INFINITY;
#pragma unroll
    for (int i = 0; i < 8; ++i) {
        int s = tid + i * 256;
        int p = pcnt[b * SS + s] - 1; if (p < 0) p = 0;
        float v = (mask[b * SS + s] != 0) ? y[(size_t)p * SS + s] : NEGV;
        beta[i] = v;
        mx = fmaxf(mx, v);
    }
    for (int off = 32; off; off >>= 1) mx = fmaxf(mx, __shfl_xor(mx, off, 64));
    if (lane == 0) rmax[wave] = mx;
    __syncthreads();
    mx = fmaxf(fmaxf(rmax[0], rmax[1]), fmaxf(rmax[2], rmax[3]));
    float sum = 0.f;
#pragma unroll
    for (int i = 0; i < 8; ++i) sum += expf(beta[i] - mx);
    for (int off = 32; off; off >>= 1) sum += __shfl_xor(sum, off, 64);
    if (lane == 0) rsum[wave] = sum;
    __syncthreads();
    sum = rsum[0] + rsum[1] + rsum[2] + rsum[3];
    const float inv = 1.f / sum;

    // ---- wave 0 builds the combined compact list for 4 chunks of 32 rows
    if (wave == 0) {
        int base = 0;
#pragma unroll
        for (int cc = 0; cc < 4; ++cc) {
            int s = grp * 128 + cc * 32 + lane;   // lane<32 valid
            float a = 0.f;
            bool nz = false;
            if (lane < 32 && mask[b * SS + s] != 0) {
                int p = pcnt[b * SS + s] - 1; if (p < 0) p = 0;
                a = expf(y[(size_t)p * SS + s] - mx) * inv;
                nz = (a != 0.f);
            }
            unsigned long long mk = __ballot(nz);
            if (nz) {
                int off = base + __popcll(mk & ((1ull << lane) - 1));
                slist[off] = s;
                aval[off] = a;
            }
            base += __popcll(mk);
        }
        if (lane == 0) mtot = base;
    }
    __syncthreads();

    // ---- weighted sum over ≤128 rows, unroll-4 (4 rows in flight per wave)
    const int m = mtot;
    const float* basep = h_i + (size_t)b * SS * HH;
    f32x4 a0 = {0,0,0,0}, a1 = {0,0,0,0}, a2 = {0,0,0,0}, a3 = {0,0,0,0};
    int i2 = 0;
    for (; i2 + 4 <= m; i2 += 4) {
        float w0 = aval[i2],     w1 = aval[i2 + 1];
        float w2 = aval[i2 + 2], w3 = aval[i2 + 3];
        float4 v0 = *reinterpret_cast<const float4*>(&basep[(size_t)slist[i2]     * HH + tid * 4]);
        float4 v1 = *reinterpret_cast<const float4*>(&basep[(size_t)slist[i2 + 1] * HH + tid * 4]);
        float4 v2 = *reinterpret_cast<const float4*>(&basep[(size_t)slist[i2 + 2] * HH + tid * 4]);
        float4 v3 = *reinterpret_cast<const float4*>(&basep[(size_t)slist[i2 + 3] * HH + tid * 4]);
        a0[0] += w0 * v0.x; a0[1] += w0 * v0.y; a0[2] += w0 * v0.z; a0[3] += w0 * v0.w;
        a1[0] += w1 * v1.x; a1[1] += w1 * v1.y; a1[2] += w1 * v1.z; a1[3] += w1 * v1.w;
        a2[0] += w2 * v2.x; a2[1] += w2 * v2.y; a2[2] += w2 * v2.z; a2[3] += w2 * v2.w;
        a3[0] += w3 * v3.x; a3[1] += w3 * v3.y; a3[2] += w3 * v3.z; a3[3] += w3 * v3.w;
    }
    for (; i2 < m; ++i2) {
        float w0 = aval[i2];
        float4 v0 = *reinterpret_cast<const float4*>(&basep[(size_t)slist[i2] * HH + tid * 4]);
        a0[0] += w0 * v0.x; a0[1] += w0 * v0.y; a0[2] += w0 * v0.z; a0[3] += w0 * v0.w;
    }
    f32x4 acc4;
    acc4[0] = (a0[0] + a1[0]) + (a2[0] + a3[0]);
    acc4[1] = (a0[1] + a1[1]) + (a2[1] + a3[1]);
    acc4[2] = (a0[2] + a1[2]) + (a2[2] + a3[2]);
    acc4[3] = (a0[3] + a1[3]) + (a2[3] + a3[3]);
    *reinterpret_cast<f32x4*>(&partial[(size_t)blk * HH + tid * 4]) = acc4;
}

// ============ K4b: out[b,h] = sum_g partial[b,g,h] ==========================
__global__ __launch_bounds__(256) void k4b_reduce(const float* __restrict__ partial,
                                                  float* __restrict__ out) {
    int i = blockIdx.x * 256 + threadIdx.x;   // 0..32767
    int b = i >> 10, h = i & (HH - 1);
    float s = 0.f;
#pragma unroll
    for (int g = 0; g < NG; ++g)
        s += partial[((size_t)(b * NG + g)) * HH + h];
    out[i] = s;
}

extern "C" void kernel_launch(void* const* d_in, const int* in_sizes, int n_in,
                              void* d_out, int out_size, void* d_ws, size_t ws_size,
                              hipStream_t stream) {
    const float* h_i  = (const float*)d_in[0];
    const float* h_t  = (const float*)d_in[1];
    const int*   mask = (const int*)d_in[2];
    const float* W    = (const float*)d_in[3];
    const float* bias = (const float*)d_in[4];
    const float* u    = (const float*)d_in[5];
    float* out = (float*)d_out;

    float* c        = (float*)d_ws;                        // 8192
    float* y        = c + BB * AA;                         // 65536
    float* partial  = y + BB * SS;                         // B*NG*H = 524288
    _Float16* W16t  = (_Float16*)(partial + BB * NG * HH); // 262144 f16
    int* sList      = (int*)(W16t + AA * HH);              // 65536
    int* cntb       = sList + BB * SS;                     // 32
    int* pcnt       = cntb + BB;                           // 65536

    k_prep<<<2208, 256, 0, stream>>>(W, h_t, bias, mask, W16t, c, sList, cntb, pcnt);
    k2_mfma<<<1024, 256, 0, stream>>>(h_i, W16t, c, u, sList, cntb, y);
    k34<<<BB * NG, 256, 0, stream>>>(h_i, y, mask, pcnt, partial);
    k4b_reduce<<<(BB * HH) / 256, 256, 0, stream>>>(partial, out);
}